// Round 1
// baseline (573.987 us; speedup 1.0000x reference)
//
#include <hip/hip_runtime.h>
#include <cfloat>
#include <cstdint>

#define B_DIM 4
#define L_DIM 2048
#define NROW (B_DIM * L_DIM)      // 8192
#define TOPK 30
#define NEDGE (NROW * TOPK)       // 245760

// workspace layout (float offsets)
#define WS_CB   0                 // 24576 floats: Cb[row][3]
#define WS_CX   24576             // 8192
#define WS_CY   32768             // 8192
#define WS_CZ   40960             // 8192
#define WS_W2T  49152             // 32768: W2t[k][f], 256x128
#define WS_TPOS 81920             // 8448:  Tpos[d][f], 66x128
#define WS_EIDX 90368             // 245760 ints

// ---------------------------------------------------------------- prep
__global__ void prep_kernel(const float* __restrict__ X,
                            const float* __restrict__ pe_w,
                            const float* __restrict__ pe_b,
                            const float* __restrict__ edge_w,
                            float* __restrict__ ws) {
  int tid = blockIdx.x * 256 + threadIdx.x;
  if (tid < NROW) {
    const float* Xr = X + (size_t)tid * 12;
    float nx = Xr[0], ny = Xr[1], nz = Xr[2];   // N
    float cx = Xr[3], cy = Xr[4], cz = Xr[5];   // C
    float ax = Xr[6], ay = Xr[7], az = Xr[8];   // Ca
    float bx = ax - nx, by = ay - ny, bz = az - nz;   // b = Ca - N
    float vx = cx - ax, vy = cy - ay, vz = cz - az;   // c = C - Ca
    float crx = by * vz - bz * vy;
    float cry = bz * vx - bx * vz;
    float crz = bx * vy - by * vx;
    ws[WS_CB + tid * 3 + 0] = -0.58273431f * crx + 0.56802827f * bx - 0.54067466f * vx + ax;
    ws[WS_CB + tid * 3 + 1] = -0.58273431f * cry + 0.56802827f * by - 0.54067466f * vy + ay;
    ws[WS_CB + tid * 3 + 2] = -0.58273431f * crz + 0.56802827f * bz - 0.54067466f * vz + az;
    ws[WS_CX + tid] = cx;
    ws[WS_CY + tid] = cy;
    ws[WS_CZ + tid] = cz;
  } else if (tid < NROW + 32768) {
    int t2 = tid - NROW;
    int k = t2 >> 7, f = t2 & 127;
    ws[WS_W2T + t2] = edge_w[f * 272 + 16 + k];
  } else if (tid < NROW + 32768 + 8448) {
    int t2 = tid - NROW - 32768;
    int d = t2 >> 7, f = t2 & 127;
    float s = 0.f;
    #pragma unroll
    for (int n = 0; n < 16; n++)
      s += edge_w[f * 272 + n] * (pe_w[n * 66 + d] + pe_b[n]);
    ws[WS_TPOS + t2] = s;
  }
}

// ---------------------------------------------------------------- top-k
__global__ void __launch_bounds__(256)
topk_kernel(const float* __restrict__ ws,
            const float* __restrict__ mask,
            int* __restrict__ eidx_out,
            float* __restrict__ idxf_out) {
  int row = blockIdx.x;
  int b = row >> 11;
  int tid = threadIdx.x;
  int lane = tid & 63;
  int wid = tid >> 6;

  __shared__ float s_dist[L_DIM];
  __shared__ unsigned long long s_wred[4];
  __shared__ float s_max[4];
  __shared__ int s_sel[TOPK];

  const float* Cx = ws + WS_CX + b * L_DIM;
  const float* Cy = ws + WS_CY + b * L_DIM;
  const float* Cz = ws + WS_CZ + b * L_DIM;

  float cix = Cx[row & 2047], ciy = Cy[row & 2047], ciz = Cz[row & 2047];
  float mi = mask[row];

  float m2loc[8];
  float dmax_loc = 0.f;
  #pragma unroll
  for (int k = 0; k < 8; k++) {
    int jj = tid + k * 256;
    float dx = Cx[jj] - cix;
    float dy = Cy[jj] - ciy;
    float dz = Cz[jj] - ciz;
    float raw = sqrtf(dx * dx + dy * dy + dz * dz + 1e-6f);
    float m2 = mi * mask[b * L_DIM + jj];
    float d = m2 * raw;
    m2loc[k] = m2;
    s_dist[jj] = d;
    dmax_loc = fmaxf(dmax_loc, d);
  }
  // block max reduce
  #pragma unroll
  for (int off = 32; off >= 1; off >>= 1)
    dmax_loc = fmaxf(dmax_loc, __shfl_xor(dmax_loc, off));
  if (lane == 0) s_max[wid] = dmax_loc;
  __syncthreads();
  float dmax = fmaxf(fmaxf(s_max[0], s_max[1]), fmaxf(s_max[2], s_max[3]));

  // mask-adjust + build local min key
  unsigned long long local_key = ~0ull;
  #pragma unroll
  for (int k = 0; k < 8; k++) {
    int jj = tid + k * 256;
    float v = s_dist[jj] + (1.f - m2loc[k]) * dmax;
    s_dist[jj] = v;
    unsigned long long key = ((unsigned long long)__float_as_uint(v) << 32) | (unsigned)jj;
    local_key = (key < local_key) ? key : local_key;
  }
  __syncthreads();

  for (int n = 0; n < TOPK; n++) {
    unsigned long long k = local_key;
    #pragma unroll
    for (int off = 32; off >= 1; off >>= 1) {
      unsigned long long o = __shfl_xor(k, off);
      k = (o < k) ? o : k;
    }
    if (lane == 0) s_wred[wid] = k;
    __syncthreads();
    unsigned long long k0 = s_wred[0];
    k0 = (s_wred[1] < k0) ? s_wred[1] : k0;
    k0 = (s_wred[2] < k0) ? s_wred[2] : k0;
    k0 = (s_wred[3] < k0) ? s_wred[3] : k0;
    int idx = (int)(k0 & 0xffffffffull);
    if (tid == 0) s_sel[n] = idx;
    if (tid == (idx & 255)) {
      s_dist[idx] = FLT_MAX;
      local_key = ~0ull;
      #pragma unroll
      for (int kk = 0; kk < 8; kk++) {
        int jj = tid + kk * 256;
        unsigned long long key =
            ((unsigned long long)__float_as_uint(s_dist[jj]) << 32) | (unsigned)jj;
        local_key = (key < local_key) ? key : local_key;
      }
    }
    __syncthreads();
  }

  if (tid < TOPK) {
    int j = s_sel[tid];
    eidx_out[row * TOPK + tid] = j;
    idxf_out[row * TOPK + tid] = (float)j;
  }
}

// ---------------------------------------------------------------- edges
__constant__ int c_pa[16] = {1,0,2,3, 1,1,1, 0,0, 3, 0,2,3, 2,3, 2};
__constant__ int c_pb[16] = {1,0,2,3, 0,2,3, 2,3, 2, 1,1,1, 0,0, 3};

__global__ void __launch_bounds__(256)
edge_kernel(const float* __restrict__ X,
            const float* __restrict__ ws,
            const int* __restrict__ ridx,
            const int* __restrict__ chain,
            const float* __restrict__ ln_g,
            const float* __restrict__ ln_b,
            float* __restrict__ out) {
  __shared__ float s_w2t[64 * 128];
  __shared__ float s_rbf[60 * 64];
  __shared__ float s_dist[60 * 16];
  __shared__ int s_pos[60];

  int t = threadIdx.x;
  int r0 = blockIdx.x * 2;
  const float* Cbw = ws + WS_CB;
  const float* W2t = ws + WS_W2T;
  const float* Tpos = ws + WS_TPOS;
  const int* eidx = (const int*)(ws + WS_EIDX);

  // phase 0: per-edge distances + positional index
  if (t < 60) {
    int e = t;
    int row = r0 + (e >= 30 ? 1 : 0);
    int kkn = e % 30;
    int bb = row >> 11;
    int j = eidx[row * TOPK + kkn];
    int jrow = bb * L_DIM + j;
    int off = ridx[row] - ridx[jrow];
    int same = (chain[row] == chain[jrow]);
    s_pos[e] = same ? min(max(off + 32, 0), 64) : 65;

    const float* Xi = X + (size_t)row * 12;
    const float* Xj = X + (size_t)jrow * 12;
    float axi[4], ayi[4], azi[4], axj[4], ayj[4], azj[4];
    #pragma unroll
    for (int a = 0; a < 3; a++) {
      axi[a] = Xi[a * 3 + 0]; ayi[a] = Xi[a * 3 + 1]; azi[a] = Xi[a * 3 + 2];
      axj[a] = Xj[a * 3 + 0]; ayj[a] = Xj[a * 3 + 1]; azj[a] = Xj[a * 3 + 2];
    }
    axi[3] = Cbw[row * 3 + 0]; ayi[3] = Cbw[row * 3 + 1]; azi[3] = Cbw[row * 3 + 2];
    axj[3] = Cbw[jrow * 3 + 0]; ayj[3] = Cbw[jrow * 3 + 1]; azj[3] = Cbw[jrow * 3 + 2];
    #pragma unroll
    for (int p = 0; p < 16; p++) {
      int a = c_pa[p], bcode = c_pb[p];
      float dx = axi[a] - axj[bcode];
      float dy = ayi[a] - ayj[bcode];
      float dz = azi[a] - azj[bcode];
      s_dist[e * 16 + p] = sqrtf(dx * dx + dy * dy + dz * dz + 1e-6f);
    }
  }
  __syncthreads();

  int f2 = t & 63;
  int eg = t >> 6;  // wave id: owns edges eg*15 .. eg*15+14

  float acc0[15], acc1[15];
  #pragma unroll
  for (int q = 0; q < 15; q++) {
    int dp = s_pos[eg * 15 + q];
    acc0[q] = Tpos[dp * 128 + f2];
    acc1[q] = Tpos[dp * 128 + 64 + f2];
  }

  for (int kc = 0; kc < 4; kc++) {
    __syncthreads();
    // stage W2t chunk [64 k][128 f]
    {
      const float4* src = (const float4*)(W2t + kc * 8192);
      float4* dst = (float4*)s_w2t;
      for (int v = t; v < 2048; v += 256) dst[v] = src[v];
    }
    // fill rbf tile [60 e][64 k]
    for (int idx = t; idx < 3840; idx += 256) {
      int e = idx >> 6, kk2 = idx & 63;
      int c = kc * 64 + kk2;
      int p = c >> 4, rr = c & 15;
      float dd = s_dist[e * 16 + p];
      float z = (dd - (2.0f + (float)rr * (20.0f / 15.0f))) * 0.8f;
      s_rbf[idx] = __expf(-z * z);
    }
    __syncthreads();
    #pragma unroll 4
    for (int kk = 0; kk < 64; kk++) {
      float w0 = s_w2t[kk * 128 + f2];
      float w1 = s_w2t[kk * 128 + 64 + f2];
      #pragma unroll
      for (int q = 0; q < 15; q++) {
        float rv = s_rbf[(eg * 15 + q) * 64 + kk];
        acc0[q] += rv * w0;
        acc1[q] += rv * w1;
      }
    }
  }

  // LayerNorm + write
  float g0 = ln_g[f2], g1 = ln_g[64 + f2];
  float bb0 = ln_b[f2], bb1 = ln_b[64 + f2];
  #pragma unroll
  for (int q = 0; q < 15; q++) {
    float s = acc0[q] + acc1[q];
    float s2 = acc0[q] * acc0[q] + acc1[q] * acc1[q];
    #pragma unroll
    for (int off = 32; off >= 1; off >>= 1) {
      s += __shfl_xor(s, off);
      s2 += __shfl_xor(s2, off);
    }
    float mu = s * (1.0f / 128.0f);
    float var = s2 * (1.0f / 128.0f) - mu * mu;
    float inv = rsqrtf(var + 1e-5f);
    int e = eg * 15 + q;
    int row = r0 + (e >= 30 ? 1 : 0);
    int kkn = e % 30;
    float* o = out + ((size_t)row * TOPK + kkn) * 128;
    o[f2] = (acc0[q] - mu) * inv * g0 + bb0;
    o[64 + f2] = (acc1[q] - mu) * inv * g1 + bb1;
  }
}

// ---------------------------------------------------------------- launch
extern "C" void kernel_launch(void* const* d_in, const int* in_sizes, int n_in,
                              void* d_out, int out_size, void* d_ws, size_t ws_size,
                              hipStream_t stream) {
  const float* X      = (const float*)d_in[0];
  const float* mask   = (const float*)d_in[1];
  const int*   ridx   = (const int*)d_in[2];
  const int*   chain  = (const int*)d_in[3];
  const float* pe_w   = (const float*)d_in[4];
  const float* pe_b   = (const float*)d_in[5];
  const float* edge_w = (const float*)d_in[6];
  const float* ln_g   = (const float*)d_in[7];
  const float* ln_b   = (const float*)d_in[8];
  float* out = (float*)d_out;
  float* ws  = (float*)d_ws;

  hipLaunchKernelGGL(prep_kernel, dim3(193), dim3(256), 0, stream,
                     X, pe_w, pe_b, edge_w, ws);
  hipLaunchKernelGGL(topk_kernel, dim3(NROW), dim3(256), 0, stream,
                     ws, mask, (int*)(ws + WS_EIDX), out + (size_t)NEDGE * 128);
  hipLaunchKernelGGL(edge_kernel, dim3(NROW / 2), dim3(256), 0, stream,
                     X, ws, ridx, chain, ln_g, ln_b, out);
}

// Round 2
// 358.498 us; speedup vs baseline: 1.6011x; 1.6011x over previous
//
#include <hip/hip_runtime.h>
#include <cfloat>
#include <cstdint>

#define B_DIM 4
#define L_DIM 2048
#define NROW (B_DIM * L_DIM)      // 8192
#define TOPK 30
#define NEDGE (NROW * TOPK)       // 245760

// workspace layout (float offsets)
#define WS_CB    0                // 24576 floats: Cb[row][3]
#define WS_CX    24576            // 8192
#define WS_CY    32768            // 8192
#define WS_CZ    40960            // 8192
#define WS_TPOS  49152            // 8448:  Tpos[d][f], 66x128 fp32
#define WS_BPACK 57600            // 16384 floats = 32768 bf16, fragment-linear
#define WS_EIDX  73984            // 245760 ints

typedef __bf16 bf16x8 __attribute__((ext_vector_type(8)));
typedef float f32x4 __attribute__((ext_vector_type(4)));

static __device__ __forceinline__ unsigned short f2bf(float x) {
  unsigned u = __float_as_uint(x);
  unsigned r = (u + 0x7fffu + ((u >> 16) & 1u)) >> 16;
  return (unsigned short)r;
}

// ---------------------------------------------------------------- prep
__global__ void prep_kernel(const float* __restrict__ X,
                            const float* __restrict__ pe_w,
                            const float* __restrict__ pe_b,
                            const float* __restrict__ edge_w,
                            float* __restrict__ ws) {
  int tid = blockIdx.x * 256 + threadIdx.x;
  if (tid < NROW) {
    const float* Xr = X + (size_t)tid * 12;
    float nx = Xr[0], ny = Xr[1], nz = Xr[2];   // N
    float cx = Xr[3], cy = Xr[4], cz = Xr[5];   // C
    float ax = Xr[6], ay = Xr[7], az = Xr[8];   // Ca
    float bx = ax - nx, by = ay - ny, bz = az - nz;   // b = Ca - N
    float vx = cx - ax, vy = cy - ay, vz = cz - az;   // c = C - Ca
    float crx = by * vz - bz * vy;
    float cry = bz * vx - bx * vz;
    float crz = bx * vy - by * vx;
    ws[WS_CB + tid * 3 + 0] = -0.58273431f * crx + 0.56802827f * bx - 0.54067466f * vx + ax;
    ws[WS_CB + tid * 3 + 1] = -0.58273431f * cry + 0.56802827f * by - 0.54067466f * vy + ay;
    ws[WS_CB + tid * 3 + 2] = -0.58273431f * crz + 0.56802827f * bz - 0.54067466f * vz + az;
    ws[WS_CX + tid] = cx;
    ws[WS_CY + tid] = cy;
    ws[WS_CZ + tid] = cz;
  } else if (tid < NROW + 8448) {
    int t2 = tid - NROW;
    int d = t2 >> 7, f = t2 & 127;
    float s = 0.f;
    #pragma unroll
    for (int n = 0; n < 16; n++)
      s += edge_w[f * 272 + n] * (pe_w[n * 66 + d] + pe_b[n]);
    ws[WS_TPOS + t2] = s;
  } else if (tid < NROW + 8448 + 16384) {
    // Bpack: bf16 fragment-linear [c(4)][nt(8)][s(2)][lane(64)][j(8)] as u32 pairs
    int i2 = tid - NROW - 8448;
    int j2 = i2 & 3;
    int lane = (i2 >> 2) & 63;
    int s = (i2 >> 8) & 1;
    int nt = (i2 >> 9) & 7;
    int c = (i2 >> 12) & 3;
    int f = nt * 16 + (lane & 15);
    int k = c * 64 + s * 32 + (lane >> 4) * 8 + j2 * 2;
    float v0 = edge_w[f * 272 + 16 + k];
    float v1 = edge_w[f * 272 + 16 + k + 1];
    unsigned out = (unsigned)f2bf(v0) | ((unsigned)f2bf(v1) << 16);
    ((unsigned*)(ws + WS_BPACK))[i2] = out;
  }
}

// ---------------------------------------------------------------- top-k
__global__ void __launch_bounds__(256)
topk_kernel(const float* __restrict__ ws,
            const float* __restrict__ mask,
            int* __restrict__ eidx_out,
            float* __restrict__ idxf_out) {
  int row = blockIdx.x;
  int b = row >> 11;
  int li = row & 2047;
  int t = threadIdx.x;
  int lane = t & 63;
  int w = t >> 6;

  __shared__ float s_red[4];
  __shared__ unsigned long long s_cand[128];

  const float* Cx = ws + WS_CX + b * L_DIM;
  const float* Cy = ws + WS_CY + b * L_DIM;
  const float* Cz = ws + WS_CZ + b * L_DIM;

  float cix = Cx[li], ciy = Cy[li], ciz = Cz[li];
  float mi = mask[row];

  float dloc[8], m2l[8];
  float dmax = 0.f;
  #pragma unroll
  for (int i = 0; i < 8; i++) {
    int j = w * 512 + i * 64 + lane;
    float dx = Cx[j] - cix;
    float dy = Cy[j] - ciy;
    float dz = Cz[j] - ciz;
    float raw = sqrtf(dx * dx + dy * dy + dz * dz + 1e-6f);
    float m2 = mi * mask[b * L_DIM + j];
    float d = m2 * raw;
    dloc[i] = d;
    m2l[i] = m2;
    dmax = fmaxf(dmax, d);
  }
  #pragma unroll
  for (int off = 32; off; off >>= 1)
    dmax = fmaxf(dmax, __shfl_xor(dmax, off));
  if (lane == 0) s_red[w] = dmax;
  __syncthreads();
  dmax = fmaxf(fmaxf(s_red[0], s_red[1]), fmaxf(s_red[2], s_red[3]));

  unsigned long long key[8];
  unsigned long long lm = ~0ull;
  #pragma unroll
  for (int i = 0; i < 8; i++) {
    float v = dloc[i] + (1.f - m2l[i]) * dmax;
    int j = w * 512 + i * 64 + lane;
    key[i] = ((unsigned long long)__float_as_uint(v) << 32) | (unsigned)j;
    lm = key[i] < lm ? key[i] : lm;
  }
  if (t < 8) s_cand[120 + t] = ~0ull;

  // wave-local top-30 (no barriers)
  for (int n = 0; n < TOPK; n++) {
    unsigned long long mn = lm;
    #pragma unroll
    for (int off = 32; off; off >>= 1) {
      unsigned long long o = __shfl_xor(mn, off);
      mn = o < mn ? o : mn;
    }
    unsigned long long nlm = ~0ull;
    #pragma unroll
    for (int i = 0; i < 8; i++) {
      key[i] = (key[i] == mn) ? ~0ull : key[i];
      nlm = key[i] < nlm ? key[i] : nlm;
    }
    lm = nlm;
    if (lane == 0) s_cand[w * TOPK + n] = mn;
  }
  __syncthreads();

  // wave 0: bitonic sort 128 candidates (2 per lane), take first 30
  if (w == 0) {
    unsigned long long c0 = s_cand[lane];
    unsigned long long c1 = s_cand[64 + lane];
    #pragma unroll
    for (int k = 2; k <= 128; k <<= 1) {
      #pragma unroll
      for (int j = k >> 1; j > 0; j >>= 1) {
        if (j >= 64) {
          unsigned long long lo = c0 < c1 ? c0 : c1;
          unsigned long long hi = c0 < c1 ? c1 : c0;
          c0 = lo; c1 = hi;
        } else {
          bool low = (lane & j) == 0;
          bool asc0 = (lane & k) == 0;
          bool asc1 = ((64 + lane) & k) == 0;
          unsigned long long p0 = __shfl_xor(c0, j);
          unsigned long long p1 = __shfl_xor(c1, j);
          unsigned long long mn0 = c0 < p0 ? c0 : p0, mx0 = c0 < p0 ? p0 : c0;
          unsigned long long mn1 = c1 < p1 ? c1 : p1, mx1 = c1 < p1 ? p1 : c1;
          c0 = (low == asc0) ? mn0 : mx0;
          c1 = (low == asc1) ? mn1 : mx1;
        }
      }
    }
    if (lane < TOPK) {
      int j = (int)(c0 & 0xffffffffull);
      eidx_out[row * TOPK + lane] = j;
      idxf_out[row * TOPK + lane] = (float)j;
    }
  }
}

// ---------------------------------------------------------------- edges
__constant__ int c_pa[16] = {1,0,2,3, 1,1,1, 0,0, 3, 0,2,3, 2,3, 2};
__constant__ int c_pb[16] = {1,0,2,3, 0,2,3, 2,3, 2, 1,1,1, 0,0, 3};

// smem union layout (bytes):
//  phase A/B: DIST [0,4096) | A frags [4096,12288) | B frags [12288,28672)
//  epilogue:  OUT tile 64 x 132 fp32 [0,33792)
//  POS (never overlapped): [33792, 34048)
#define SM_DIST 0
#define SM_A    4096
#define SM_B    12288
#define SM_POS  33792
#define SM_TOTAL 34048

__global__ void __launch_bounds__(256)
edge_kernel(const float* __restrict__ X,
            const float* __restrict__ ws,
            const int* __restrict__ ridx,
            const int* __restrict__ chain,
            const float* __restrict__ ln_g,
            const float* __restrict__ ln_b,
            float* __restrict__ out) {
  __shared__ __align__(16) char smem[SM_TOTAL];
  float* s_dist = (float*)(smem + SM_DIST);
  int* s_pos = (int*)(smem + SM_POS);
  float* s_out = (float*)smem;  // stride 132 floats

  int t = threadIdx.x;
  int r0 = blockIdx.x * 2;
  const float* Cbw = ws + WS_CB;
  const float* Tpos = ws + WS_TPOS;
  const int* eidx = (const int*)(ws + WS_EIDX);

  // phase 0: per-edge distances + positional index
  if (t < 64) {
    if (t < 60) {
      int e = t;
      int row = r0 + (e >= 30 ? 1 : 0);
      int kkn = e % 30;
      int bb = row >> 11;
      int j = eidx[row * TOPK + kkn];
      int jrow = bb * L_DIM + j;
      int off = ridx[row] - ridx[jrow];
      int same = (chain[row] == chain[jrow]);
      s_pos[e] = same ? min(max(off + 32, 0), 64) : 65;

      const float* Xi = X + (size_t)row * 12;
      const float* Xj = X + (size_t)jrow * 12;
      float axi[4], ayi[4], azi[4], axj[4], ayj[4], azj[4];
      #pragma unroll
      for (int a = 0; a < 3; a++) {
        axi[a] = Xi[a * 3 + 0]; ayi[a] = Xi[a * 3 + 1]; azi[a] = Xi[a * 3 + 2];
        axj[a] = Xj[a * 3 + 0]; ayj[a] = Xj[a * 3 + 1]; azj[a] = Xj[a * 3 + 2];
      }
      axi[3] = Cbw[row * 3 + 0]; ayi[3] = Cbw[row * 3 + 1]; azi[3] = Cbw[row * 3 + 2];
      axj[3] = Cbw[jrow * 3 + 0]; ayj[3] = Cbw[jrow * 3 + 1]; azj[3] = Cbw[jrow * 3 + 2];
      #pragma unroll
      for (int p = 0; p < 16; p++) {
        int a = c_pa[p], bc = c_pb[p];
        float dx = axi[a] - axj[bc];
        float dy = ayi[a] - ayj[bc];
        float dz = azi[a] - azj[bc];
        s_dist[e * 16 + p] = sqrtf(dx * dx + dy * dy + dz * dz + 1e-6f);
      }
    } else {
      s_pos[t] = 0;
      #pragma unroll
      for (int p = 0; p < 16; p++) s_dist[t * 16 + p] = 8.0f;
    }
  }
  __syncthreads();

  int lane = t & 63;
  int w = t >> 6;

  f32x4 zero4 = {0.f, 0.f, 0.f, 0.f};
  f32x4 acc[8];
  #pragma unroll
  for (int nt = 0; nt < 8; nt++) acc[nt] = zero4;

  for (int c = 0; c < 4; c++) {
    // stage B chunk (16 KB) fragment-linear from global
    {
      const float4* src = (const float4*)(ws + WS_BPACK) + c * 1024;
      float4* dst = (float4*)(smem + SM_B);
      #pragma unroll
      for (int v = 0; v < 4; v++) dst[t + v * 256] = src[t + v * 256];
    }
    // fill A fragment-linear: [w(4)][s(2)][lane(64)][j(8)] bf16, as u32 pairs
    {
      unsigned* ap = (unsigned*)(smem + SM_A);
      #pragma unroll
      for (int v = 0; v < 8; v++) {
        int i2 = t + v * 256;
        int j2 = i2 & 3;
        int al = (i2 >> 2) & 63;
        int s = (i2 >> 8) & 1;
        int aw = (i2 >> 9) & 3;
        int m = aw * 16 + (al & 15);
        int k = c * 64 + s * 32 + (al >> 4) * 8 + j2 * 2;
        float d = s_dist[m * 16 + (k >> 4)];
        float rr = (float)(k & 15);
        float z0 = (d - (2.0f + rr * (20.0f / 15.0f))) * 0.8f;
        float z1 = (d - (2.0f + (rr + 1.0f) * (20.0f / 15.0f))) * 0.8f;
        float v0 = __expf(-z0 * z0);
        float v1 = __expf(-z1 * z1);
        ap[i2] = (unsigned)f2bf(v0) | ((unsigned)f2bf(v1) << 16);
      }
    }
    __syncthreads();
    // MFMA: 2 k-steps x 8 n-tiles
    #pragma unroll
    for (int s = 0; s < 2; s++) {
      bf16x8 a = *(const bf16x8*)(smem + SM_A + ((w * 2 + s) * 64 + lane) * 16);
      #pragma unroll
      for (int nt = 0; nt < 8; nt++) {
        bf16x8 bfr = *(const bf16x8*)(smem + SM_B + ((nt * 2 + s) * 64 + lane) * 16);
        acc[nt] = __builtin_amdgcn_mfma_f32_16x16x32_bf16(a, bfr, acc[nt], 0, 0, 0);
      }
    }
    __syncthreads();
  }

  // epilogue: spill accumulators to LDS tile [64 m][132 f]
  int quad = lane >> 4;
  int col0 = lane & 15;
  #pragma unroll
  for (int nt = 0; nt < 8; nt++) {
    #pragma unroll
    for (int r = 0; r < 4; r++) {
      int m = w * 16 + quad * 4 + r;
      s_out[m * 132 + nt * 16 + col0] = acc[nt][r];
    }
  }
  // wave-local LN over own 16 rows (no cross-wave deps)
  __builtin_amdgcn_s_waitcnt(0);  // lgkm drain for own ds_writes (compiler also handles)
  float g0 = ln_g[lane], g1 = ln_g[64 + lane];
  float bb0 = ln_b[lane], bb1 = ln_b[64 + lane];
  #pragma unroll
  for (int q = 0; q < 16; q++) {
    int e = w * 16 + q;
    if (e < 60) {
      int dp = s_pos[e];
      float a0 = s_out[e * 132 + lane] + Tpos[dp * 128 + lane];
      float a1 = s_out[e * 132 + 64 + lane] + Tpos[dp * 128 + 64 + lane];
      float s = a0 + a1;
      float s2 = a0 * a0 + a1 * a1;
      #pragma unroll
      for (int off = 32; off; off >>= 1) {
        s += __shfl_xor(s, off);
        s2 += __shfl_xor(s2, off);
      }
      float mu = s * (1.0f / 128.0f);
      float var = s2 * (1.0f / 128.0f) - mu * mu;
      float inv = rsqrtf(var + 1e-5f);
      int row = r0 + (e >= 30 ? 1 : 0);
      int kn = e % 30;
      float* o = out + ((size_t)row * TOPK + kn) * 128;
      o[lane] = (a0 - mu) * inv * g0 + bb0;
      o[64 + lane] = (a1 - mu) * inv * g1 + bb1;
    }
  }
}

// ---------------------------------------------------------------- launch
extern "C" void kernel_launch(void* const* d_in, const int* in_sizes, int n_in,
                              void* d_out, int out_size, void* d_ws, size_t ws_size,
                              hipStream_t stream) {
  const float* X      = (const float*)d_in[0];
  const float* mask   = (const float*)d_in[1];
  const int*   ridx   = (const int*)d_in[2];
  const int*   chain  = (const int*)d_in[3];
  const float* pe_w   = (const float*)d_in[4];
  const float* pe_b   = (const float*)d_in[5];
  const float* edge_w = (const float*)d_in[6];
  const float* ln_g   = (const float*)d_in[7];
  const float* ln_b   = (const float*)d_in[8];
  float* out = (float*)d_out;
  float* ws  = (float*)d_ws;

  hipLaunchKernelGGL(prep_kernel, dim3(129), dim3(256), 0, stream,
                     X, pe_w, pe_b, edge_w, ws);
  hipLaunchKernelGGL(topk_kernel, dim3(NROW), dim3(256), 0, stream,
                     ws, mask, (int*)(ws + WS_EIDX), out + (size_t)NEDGE * 128);
  hipLaunchKernelGGL(edge_kernel, dim3(NROW / 2), dim3(256), 0, stream,
                     X, ws, ridx, chain, ln_g, ln_b, out);
}

// Round 3
// 300.883 us; speedup vs baseline: 1.9077x; 1.1915x over previous
//
#include <hip/hip_runtime.h>
#include <cfloat>
#include <cstdint>

#define B_DIM 4
#define L_DIM 2048
#define NROW (B_DIM * L_DIM)      // 8192
#define TOPK 30
#define NEDGE (NROW * TOPK)       // 245760

// workspace layout (float offsets)
#define WS_CB    0                // 24576 floats: Cb[row][3]
#define WS_CX    24576            // 8192
#define WS_CY    32768            // 8192
#define WS_CZ    40960            // 8192
#define WS_TPOS  49152            // 8448:  Tpos[d][f], 66x128 fp32
#define WS_BPACK 57600            // 16384 floats = 32768 bf16, fragment-linear
#define WS_EIDX  73984            // 245760 ints

typedef __bf16 bf16x8 __attribute__((ext_vector_type(8)));
typedef __bf16 bf16x2 __attribute__((ext_vector_type(2)));
typedef float f32x4 __attribute__((ext_vector_type(4)));

static __device__ __forceinline__ unsigned short f2bf(float x) {
  unsigned u = __float_as_uint(x);
  unsigned r = (u + 0x7fffu + ((u >> 16) & 1u)) >> 16;
  return (unsigned short)r;
}

static __device__ __forceinline__ unsigned pk_bf16(float a, float b) {
#if __has_builtin(__builtin_amdgcn_cvt_pk_bf16_f32)
  union { bf16x2 v; unsigned u; } cv;
  cv.v = __builtin_amdgcn_cvt_pk_bf16_f32(a, b);
  return cv.u;
#else
  return (unsigned)f2bf(a) | ((unsigned)f2bf(b) << 16);
#endif
}

// ---------------------------------------------------------------- prep
__global__ void prep_kernel(const float* __restrict__ X,
                            const float* __restrict__ pe_w,
                            const float* __restrict__ pe_b,
                            const float* __restrict__ edge_w,
                            float* __restrict__ ws) {
  int tid = blockIdx.x * 256 + threadIdx.x;
  if (tid < NROW) {
    const float* Xr = X + (size_t)tid * 12;
    float nx = Xr[0], ny = Xr[1], nz = Xr[2];   // N
    float cx = Xr[3], cy = Xr[4], cz = Xr[5];   // C
    float ax = Xr[6], ay = Xr[7], az = Xr[8];   // Ca
    float bx = ax - nx, by = ay - ny, bz = az - nz;   // b = Ca - N
    float vx = cx - ax, vy = cy - ay, vz = cz - az;   // c = C - Ca
    float crx = by * vz - bz * vy;
    float cry = bz * vx - bx * vz;
    float crz = bx * vy - by * vx;
    ws[WS_CB + tid * 3 + 0] = -0.58273431f * crx + 0.56802827f * bx - 0.54067466f * vx + ax;
    ws[WS_CB + tid * 3 + 1] = -0.58273431f * cry + 0.56802827f * by - 0.54067466f * vy + ay;
    ws[WS_CB + tid * 3 + 2] = -0.58273431f * crz + 0.56802827f * bz - 0.54067466f * vz + az;
    ws[WS_CX + tid] = cx;
    ws[WS_CY + tid] = cy;
    ws[WS_CZ + tid] = cz;
  } else if (tid < NROW + 8448) {
    int t2 = tid - NROW;
    int d = t2 >> 7, f = t2 & 127;
    float s = 0.f;
    #pragma unroll
    for (int n = 0; n < 16; n++)
      s += edge_w[f * 272 + n] * (pe_w[n * 66 + d] + pe_b[n]);
    ws[WS_TPOS + t2] = s;
  } else if (tid < NROW + 8448 + 16384) {
    // Bpack: bf16 fragment-linear [c(4)][nt(8)][s(2)][lane(64)][j(8)] as u32 pairs
    int i2 = tid - NROW - 8448;
    int j2 = i2 & 3;
    int lane = (i2 >> 2) & 63;
    int s = (i2 >> 8) & 1;
    int nt = (i2 >> 9) & 7;
    int c = (i2 >> 12) & 3;
    int f = nt * 16 + (lane & 15);
    int k = c * 64 + s * 32 + (lane >> 4) * 8 + j2 * 2;
    float v0 = edge_w[f * 272 + 16 + k];
    float v1 = edge_w[f * 272 + 16 + k + 1];
    unsigned out = (unsigned)f2bf(v0) | ((unsigned)f2bf(v1) << 16);
    ((unsigned*)(ws + WS_BPACK))[i2] = out;
  }
}

// ---------------------------------------------------------------- top-k
// 8 groups of 32 lanes, each selects top-30 of its 256 elements via
// sorted-register-queue pop tournament; truncated-bitonic final merge.
#define CAS64(a, b) { bool lt = (a) < (b); \
  unsigned long long lo = lt ? (a) : (b), hi = lt ? (b) : (a); (a) = lo; (b) = hi; }

__global__ void __launch_bounds__(256)
topk_kernel(const float* __restrict__ ws,
            const float* __restrict__ mask,
            int* __restrict__ eidx_out,
            float* __restrict__ idxf_out) {
  int row = blockIdx.x;
  int b = row >> 11;
  int li = row & 2047;
  int t = threadIdx.x;
  int lane = t & 63;
  int w = t >> 6;
  int g = t >> 5;        // group 0..7 (256 elements each)
  int l32 = t & 31;

  __shared__ float s_red[4];
  __shared__ unsigned long long s_cand[256];

  const float* Cx = ws + WS_CX + b * L_DIM;
  const float* Cy = ws + WS_CY + b * L_DIM;
  const float* Cz = ws + WS_CZ + b * L_DIM;

  float cix = Cx[li], ciy = Cy[li], ciz = Cz[li];
  float mi = mask[row];

  float dloc[8], m2l[8];
  float dmax = 0.f;
  #pragma unroll
  for (int i = 0; i < 8; i++) {
    int j = g * 256 + i * 32 + l32;
    float dx = Cx[j] - cix;
    float dy = Cy[j] - ciy;
    float dz = Cz[j] - ciz;
    float raw = sqrtf(dx * dx + dy * dy + dz * dz + 1e-6f);
    float m2 = mi * mask[b * L_DIM + j];
    float d = m2 * raw;
    dloc[i] = d;
    m2l[i] = m2;
    dmax = fmaxf(dmax, d);
  }
  #pragma unroll
  for (int off = 32; off; off >>= 1)
    dmax = fmaxf(dmax, __shfl_xor(dmax, off));
  if (lane == 0) s_red[w] = dmax;
  __syncthreads();
  dmax = fmaxf(fmaxf(s_red[0], s_red[1]), fmaxf(s_red[2], s_red[3]));

  unsigned long long key[8];
  #pragma unroll
  for (int i = 0; i < 8; i++) {
    float v = dloc[i] + (1.f - m2l[i]) * dmax;
    int j = g * 256 + i * 32 + l32;
    key[i] = ((unsigned long long)__float_as_uint(v) << 32) | (unsigned)j;
  }
  // sort 8 keys ascending (19-comparator network)
  CAS64(key[0], key[1]); CAS64(key[2], key[3]); CAS64(key[4], key[5]); CAS64(key[6], key[7]);
  CAS64(key[0], key[2]); CAS64(key[1], key[3]); CAS64(key[4], key[6]); CAS64(key[5], key[7]);
  CAS64(key[1], key[2]); CAS64(key[5], key[6]); CAS64(key[0], key[4]); CAS64(key[3], key[7]);
  CAS64(key[1], key[5]); CAS64(key[2], key[6]);
  CAS64(key[1], key[4]); CAS64(key[3], key[6]);
  CAS64(key[2], key[4]); CAS64(key[3], key[5]);
  CAS64(key[3], key[4]);

  unsigned cv = (unsigned)(key[0] >> 32);
  unsigned cj = (unsigned)key[0];
  unsigned long long myout = ~0ull;

  for (int n = 0; n < TOPK; n++) {
    unsigned mv = cv;
    #pragma unroll
    for (int off = 16; off; off >>= 1) {
      unsigned o = __shfl_xor(mv, off, 32);
      mv = o < mv ? o : mv;
    }
    unsigned tj = (cv == mv) ? cj : 0xffffffffu;
    unsigned mj = tj;
    #pragma unroll
    for (int off = 16; off; off >>= 1) {
      unsigned o = __shfl_xor(mj, off, 32);
      mj = o < mj ? o : mj;
    }
    if (l32 == n) myout = ((unsigned long long)mv << 32) | mj;
    if (cv == mv && cj == mj) {
      #pragma unroll
      for (int i = 0; i < 7; i++) key[i] = key[i + 1];
      key[7] = ~0ull;
      cv = (unsigned)(key[0] >> 32);
      cj = (unsigned)key[0];
    }
  }
  s_cand[g * 32 + l32] = (l32 < TOPK) ? myout : ~0ull;
  __syncthreads();

  // wave 0: merge 8 sorted-32 runs via truncated bitonic merges
  if (w == 0) {
    unsigned long long c0 = s_cand[lane];
    unsigned long long c1 = s_cand[64 + lane];
    unsigned long long c2 = s_cand[128 + lane];
    unsigned long long c3 = s_cand[192 + lane];
    bool lowhalf = lane < 32;

    #define MERGE32(c) { \
      unsigned long long p = __shfl_xor((c), 63); \
      (c) = (c) < p ? (c) : p; \
      _Pragma("unroll") \
      for (int j = 16; j; j >>= 1) { \
        unsigned long long q = __shfl_xor((c), j); \
        bool up = (lane & j) == 0; \
        unsigned long long mn = (c) < q ? (c) : q; \
        unsigned long long mx = (c) < q ? q : (c); \
        (c) = up ? mn : mx; \
      } }

    MERGE32(c0); MERGE32(c1); MERGE32(c2); MERGE32(c3);
    c0 = lowhalf ? c0 : c1;
    c1 = lowhalf ? c2 : c3;
    MERGE32(c0); MERGE32(c1);
    c0 = lowhalf ? c0 : c1;
    MERGE32(c0);

    if (lane < TOPK) {
      int j = (int)(c0 & 0xffffffffull);
      eidx_out[row * TOPK + lane] = j;
      idxf_out[row * TOPK + lane] = (float)j;
    }
  }
}

// ---------------------------------------------------------------- edges
// atom-pair codes, 4 bits each, p=0..15 (0=N,1=C,2=Ca,3=Cb)
#define PA_BITS 0x2323203001113201ull
#define PB_BITS 0x3001112323203201ull

// smem layout (bytes): DIST 64x17 fp32 [0,4352) | A [4352,12544) |
//                      B [12544,28928) | POS [28928,29184)
#define SM_DIST 0
#define SM_A    4352
#define SM_B    12544
#define SM_POS  28928
#define SM_TOTAL 29184

__global__ void __launch_bounds__(256)
edge_kernel(const float* __restrict__ X,
            const float* __restrict__ ws,
            const int* __restrict__ ridx,
            const int* __restrict__ chain,
            const float* __restrict__ ln_g,
            const float* __restrict__ ln_b,
            float* __restrict__ out) {
  __shared__ __align__(16) char smem[SM_TOTAL];
  float* s_dist = (float*)(smem + SM_DIST);   // [e][17], p in 0..15
  int* s_pos = (int*)(smem + SM_POS);

  int t = threadIdx.x;
  int r0 = blockIdx.x * 2;
  const float* Cbw = ws + WS_CB;
  const float* Tpos = ws + WS_TPOS;
  const int* eidx = (const int*)(ws + WS_EIDX);

  // phase 0: per-edge distances + positional index (4 threads per edge)
  if (t < 240) {
    int e = t >> 2, q = t & 3;
    int row = r0 + (e >= 30 ? 1 : 0);
    int kn = e - (e >= 30 ? 30 : 0);
    int bb = row >> 11;
    int j = eidx[row * TOPK + kn];
    int jrow = bb * L_DIM + j;
    if (q == 0) {
      int off = ridx[row] - ridx[jrow];
      int same = (chain[row] == chain[jrow]);
      s_pos[e] = same ? min(max(off + 32, 0), 64) : 65;
    }
    const float4* Xi4 = (const float4*)(X + (size_t)row * 12);
    const float4* Xj4 = (const float4*)(X + (size_t)jrow * 12);
    float4 i0 = Xi4[0], i1 = Xi4[1];
    float4 j0 = Xj4[0], j1 = Xj4[1];
    float i2x = X[(size_t)row * 12 + 8];
    float j2x = X[(size_t)jrow * 12 + 8];
    float axi[4], ayi[4], azi[4], axj[4], ayj[4], azj[4];
    axi[0] = i0.x; ayi[0] = i0.y; azi[0] = i0.z;        // N
    axi[1] = i0.w; ayi[1] = i1.x; azi[1] = i1.y;        // C
    axi[2] = i1.z; ayi[2] = i1.w; azi[2] = i2x;         // Ca
    axi[3] = Cbw[row * 3 + 0]; ayi[3] = Cbw[row * 3 + 1]; azi[3] = Cbw[row * 3 + 2];
    axj[0] = j0.x; ayj[0] = j0.y; azj[0] = j0.z;
    axj[1] = j0.w; ayj[1] = j1.x; azj[1] = j1.y;
    axj[2] = j1.z; ayj[2] = j1.w; azj[2] = j2x;
    axj[3] = Cbw[jrow * 3 + 0]; ayj[3] = Cbw[jrow * 3 + 1]; azj[3] = Cbw[jrow * 3 + 2];
    #pragma unroll
    for (int u = 0; u < 4; u++) {
      int p = q * 4 + u;
      int a = (int)((PA_BITS >> (p * 4)) & 7);
      int bc = (int)((PB_BITS >> (p * 4)) & 7);
      float dx = axi[a] - axj[bc];
      float dy = ayi[a] - ayj[bc];
      float dz = azi[a] - azj[bc];
      s_dist[e * 17 + p] = sqrtf(dx * dx + dy * dy + dz * dz + 1e-6f);
    }
  } else {
    int t2 = t - 240;        // pad edges 60..63
    int e = 60 + (t2 >> 2), q = t2 & 3;
    if (q == 0) s_pos[e] = 0;
    #pragma unroll
    for (int u = 0; u < 4; u++) s_dist[e * 17 + q * 4 + u] = 8.0f;
  }
  __syncthreads();

  int lane = t & 63;
  int w = t >> 6;

  f32x4 zero4 = {0.f, 0.f, 0.f, 0.f};
  f32x4 acc[8];
  #pragma unroll
  for (int nt = 0; nt < 8; nt++) acc[nt] = zero4;

  // RBF constants: exp(-((d-mu_r)/1.25)^2) = exp2(-(d*C1 - (2+r*4/3)*C1)^2)
  // with C1 = 0.8*sqrt(log2 e)
  const float C1 = 0.96089792702916f;        // 0.8 * 1.2011224087864498
  const float DC = 1.28119723603888f;        // (4/3) * C1
  const float B0 = -1.92179585405832f;       // -2 * C1

  for (int c = 0; c < 4; c++) {
    // stage B chunk (16 KB) fragment-linear from global
    {
      const float4* src = (const float4*)(ws + WS_BPACK) + c * 1024;
      float4* dst = (float4*)(smem + SM_B);
      #pragma unroll
      for (int v = 0; v < 4; v++) dst[t + v * 256] = src[t + v * 256];
    }
    // fill A fragment-linear: [w(4)][s(2)][lane(64)][j(8)] bf16, as u32 pairs
    {
      unsigned* ap = (unsigned*)(smem + SM_A);
      #pragma unroll
      for (int v = 0; v < 8; v++) {
        int i2 = t + v * 256;
        int j2 = i2 & 3;
        int al = (i2 >> 2) & 63;
        int s = (i2 >> 8) & 1;
        int aw = (i2 >> 9) & 3;
        int m = aw * 16 + (al & 15);
        int k = c * 64 + s * 32 + (al >> 4) * 8 + j2 * 2;
        float d = s_dist[m * 17 + (k >> 4)];
        float rrf = (float)(k & 15);
        float base = fmaf(rrf, -DC, B0);
        float zs0 = fmaf(d, C1, base);
        float zs1 = zs0 - DC;
        float v0 = __builtin_exp2f(-zs0 * zs0);
        float v1 = __builtin_exp2f(-zs1 * zs1);
        ap[i2] = pk_bf16(v0, v1);
      }
    }
    __syncthreads();
    // MFMA: 2 k-steps x 8 n-tiles
    #pragma unroll
    for (int s = 0; s < 2; s++) {
      bf16x8 a = *(const bf16x8*)(smem + SM_A + ((w * 2 + s) * 64 + lane) * 16);
      #pragma unroll
      for (int nt = 0; nt < 8; nt++) {
        bf16x8 bfr = *(const bf16x8*)(smem + SM_B + ((nt * 2 + s) * 64 + lane) * 16);
        acc[nt] = __builtin_amdgcn_mfma_f32_16x16x32_bf16(a, bfr, acc[nt], 0, 0, 0);
      }
    }
    __syncthreads();
  }

  // epilogue: LN directly from accumulator layout.
  // acc[nt][r] = C[m][f], m = w*16 + quad*4 + r, f = nt*16 + col0
  int quad = lane >> 4;
  int col0 = lane & 15;
  #pragma unroll
  for (int r = 0; r < 4; r++) {
    int e = w * 16 + quad * 4 + r;
    bool live = (e < 60);
    int dp = live ? s_pos[e] : 0;
    const float* tp = Tpos + dp * 128;
    float vv[8];
    float s = 0.f, s2 = 0.f;
    #pragma unroll
    for (int nt = 0; nt < 8; nt++) {
      float x = acc[nt][r] + tp[nt * 16 + col0];
      vv[nt] = x;
      s += x;
      s2 += x * x;
    }
    #pragma unroll
    for (int off = 8; off; off >>= 1) {
      s += __shfl_xor(s, off, 16);
      s2 += __shfl_xor(s2, off, 16);
    }
    float mu = s * (1.0f / 128.0f);
    float var = s2 * (1.0f / 128.0f) - mu * mu;
    float inv = rsqrtf(var + 1e-5f);
    if (live) {
      int row = r0 + (e >= 30 ? 1 : 0);
      int kn = e - (e >= 30 ? 30 : 0);
      float* o = out + ((size_t)row * TOPK + kn) * 128;
      #pragma unroll
      for (int nt = 0; nt < 8; nt++) {
        int f = nt * 16 + col0;
        o[f] = (vv[nt] - mu) * inv * ln_g[f] + ln_b[f];
      }
    }
  }
}

// ---------------------------------------------------------------- launch
extern "C" void kernel_launch(void* const* d_in, const int* in_sizes, int n_in,
                              void* d_out, int out_size, void* d_ws, size_t ws_size,
                              hipStream_t stream) {
  const float* X      = (const float*)d_in[0];
  const float* mask   = (const float*)d_in[1];
  const int*   ridx   = (const int*)d_in[2];
  const int*   chain  = (const int*)d_in[3];
  const float* pe_w   = (const float*)d_in[4];
  const float* pe_b   = (const float*)d_in[5];
  const float* edge_w = (const float*)d_in[6];
  const float* ln_g   = (const float*)d_in[7];
  const float* ln_b   = (const float*)d_in[8];
  float* out = (float*)d_out;
  float* ws  = (float*)d_ws;

  hipLaunchKernelGGL(prep_kernel, dim3(129), dim3(256), 0, stream,
                     X, pe_w, pe_b, edge_w, ws);
  hipLaunchKernelGGL(topk_kernel, dim3(NROW), dim3(256), 0, stream,
                     ws, mask, (int*)(ws + WS_EIDX), out + (size_t)NEDGE * 128);
  hipLaunchKernelGGL(edge_kernel, dim3(NROW / 2), dim3(256), 0, stream,
                     X, ws, ridx, chain, ln_g, ln_b, out);
}